// Round 9
// baseline (133.654 us; speedup 1.0000x reference)
//
#include <hip/hip_runtime.h>
#include <hip/hip_bf16.h>

// B=4, L=1024, H=8, E=D=64
#define NB 4
#define NL 1024
#define NH 8
#define NE 64
#define NPRIOR (NB * NH * NL)   // 32768 prior rows (= 512 blocks x 64 exactly)

typedef __bf16 bf16x8_t __attribute__((ext_vector_type(8)));
typedef __bf16 bf16x4_t __attribute__((ext_vector_type(4)));
typedef float f32x4_t __attribute__((ext_vector_type(4)));

// XOR swizzle (T2): elem ^= (row&7)<<3 spreads 128B-stride rows over banks.
__device__ __forceinline__ int kidx(int row, int col) {   // 64-wide tiles
    return (row << 6) + (col ^ ((row & 7) << 3));
}
__device__ __forceinline__ int pidx(int row, int col) {   // 1024-wide P tile
    return (row << 10) + (col ^ ((row & 7) << 3));
}

// T4-style barrier: drain LDS ops (visibility) but leave global loads/stores
// in flight (no vmcnt(0) drain like __syncthreads).
#define BAR() do { asm volatile("s_waitcnt lgkmcnt(0)" ::: "memory"); \
                   __builtin_amdgcn_s_barrier();                      \
                   asm volatile("" ::: "memory"); } while (0)

// 512 blocks (2/CU, ~73 KB LDS), 4 waves. Block (p=bid&31, jp=bid>>5) owns the
// balanced row-tile pair (31-jp, jp): 17 staged rounds per pass, identical for
// every block. Pass A: stage K -> QK^T MFMA -> e=exp(masked score) once into
// Pl (64 KB) + f32 row sums. Pass B: stage V -> PV MFMA (unnormalized P).
// STORE SMOOTHING (new vs the 87us r5 kernel): every round of BOTH passes
// streams ~24-32 KB of output — pass A rounds write zero-tail ser slabs
// (rinv-independent) + 2 prior rows; pass B rounds write their own 8 KB
// normalized ser slab (from Pl, rinv known) + 2 prior rows. No end-of-tile
// burst sweep; the per-CU write pipe (~11 B/cy) never goes idle.
__global__ __launch_bounds__(256) void fused_kernel(
    const float* __restrict__ Qg, const float* __restrict__ Kg,
    const float* __restrict__ Vg, const float* __restrict__ Sgm,
    float* __restrict__ outV, float* __restrict__ outSer,
    float* __restrict__ outP, float* __restrict__ outSig)
{
    __shared__ __bf16 Pl[32 * 1024];   // 64 KB e-values for the 32-row strip
    __shared__ __bf16 KV[64 * 64];     // 8 KB shared Q/K/V staging
    __shared__ float rsum[4][16];
    __shared__ float rinvs[32];
    __shared__ float sgl[64], cstl[64], nil[64];   // prior per-row constants

    const int bid = blockIdx.x;        // 0..511
    const int p  = bid & 31;           // b*8 + h (same-p blocks share an XCD)
    const int jp = bid >> 5;           // 0..15 pair index
    const int h = p & 7, b = p >> 3;
    const int tid = threadIdx.x;
    const int lane = tid & 63, wave = tid >> 6;
    const int l16 = lane & 15, lq = lane >> 4;
    const int rg  = wave >> 1;         // query-group (16 rows) 0/1
    const int nsb = (wave & 1) << 1;   // key/col-group base: 0 or 2
    const int rowstride = NH * NE;     // 512 floats per (b,l) row

    const float* Qb = Qg + ((size_t)b * NL) * rowstride + h * NE;
    const float* Kb = Kg + ((size_t)b * NL) * rowstride + h * NE;
    const float* Vb = Vg + ((size_t)b * NL) * rowstride + h * NE;
    float* ser = outSer + ((size_t)p << 20);
    const float scale = 0.125f;        // 1/sqrt(64)

    const int srow = tid >> 3;         // ser-slab row 0..31
    const int scol = (tid & 7) << 3;   // ser-slab col base (8 floats/thread)

    // ---- prior constants for this block's 64 rows ----
    if (tid < 64) {
        const int g  = (bid << 6) + tid;
        const int i  = g & (NL - 1);
        const int ph = g >> 10;
        const float s   = Sgm[((size_t)(ph >> 3) * NL + i) * NH + (ph & 7)];
        const float sig = 1.f / (1.f + __expf(-5.f * s)) + 1e-5f;
        // 3^sig - 1 via expm1 (avoids cancellation at sig ~ 1e-5)
        const float sg  = expm1f(sig * 1.0986122886681098f);
        sgl[tid]  = sg;
        cstl[tid] = 0.3989422804014327f / sg;
        nil[tid]  = -0.5f / (sg * sg);
    }

    int prow = 0;
    auto emit2 = [&]() {               // 2 prior+sig rows (16 KB) per round
        if (prow < 64) {
            #pragma unroll
            for (int c = 0; c < 2; ++c) {
                const int lr = prow + c;
                const int g  = (bid << 6) + lr;
                const int i  = g & (NL - 1);
                const int ph = g >> 10;
                const float sg  = sgl[lr];
                const float cst = cstl[lr];
                const float ni  = nil[lr];
                const size_t ob = ((size_t)ph << 20) + ((size_t)i << 10);
                const int j0 = tid << 2;
                const float fd = (float)(i - j0);
                f32x4_t pr;
                pr.x = cst * __expf(fd * fd * ni);
                const float f1 = fd - 1.f; pr.y = cst * __expf(f1 * f1 * ni);
                const float f2 = fd - 2.f; pr.z = cst * __expf(f2 * f2 * ni);
                const float f3 = fd - 3.f; pr.w = cst * __expf(f3 * f3 * ni);
                __builtin_nontemporal_store(pr, (f32x4_t*)(outP + ob + j0));
                f32x4_t sv = {sg, sg, sg, sg};
                __builtin_nontemporal_store(sv, (f32x4_t*)(outSig + ob + j0));
            }
            prow += 2;
        }
    };

    // ---- zero-tail ser slabs (rinv-independent, writable anytime) ----
    const int tA = 31 - jp, tB = jp;
    const int nctA = (tA + 2) >> 1, nctB = (tB + 2) >> 1;
    const int tailA = 16 - nctA;       // tailA + tailB = 15
    int zs = 0;
    auto zslab = [&]() {               // one 8 KB zero slab per pass-A round
        if (zs < 15) {
            int t_, c_;
            if (zs < tailA) { t_ = tA; c_ = nctA + zs; }
            else            { t_ = tB; c_ = nctB + (zs - tailA); }
            float* dst = ser + ((size_t)((t_ << 5) + srow) << 10) + (c_ << 6) + scol;
            f32x4_t z = {0.f, 0.f, 0.f, 0.f};
            __builtin_nontemporal_store(z, (f32x4_t*)dst);
            __builtin_nontemporal_store(z, (f32x4_t*)(dst + 4));
            ++zs;
        }
    };

    float4 preK[4], preV[4];
    auto loadT = [&](const float* base, int ct, float4 (&dst)[4]) {
        const float* src = base + ((size_t)(ct << 6)) * rowstride;
        #pragma unroll
        for (int it = 0; it < 4; ++it) {
            int g = tid + (it << 8);
            int row = g >> 4, c4 = (g & 15) << 2;
            dst[it] = *(const float4*)(src + (size_t)row * rowstride + c4);
        }
    };
    auto writeK = [&]() {
        #pragma unroll
        for (int it = 0; it < 4; ++it) {
            int g = tid + (it << 8);
            int row = g >> 4, c4 = (g & 15) << 2;
            bf16x4_t w;
            w[0] = (__bf16)preK[it].x; w[1] = (__bf16)preK[it].y;
            w[2] = (__bf16)preK[it].z; w[3] = (__bf16)preK[it].w;
            *(bf16x4_t*)(KV + kidx(row, c4)) = w;
        }
    };
    auto writeVt = [&]() {   // transposed: KV[d][j]
        #pragma unroll
        for (int it = 0; it < 4; ++it) {
            int g = tid + (it << 8);
            int row = g >> 4, c4 = (g & 15) << 2;   // row=j, c4=d
            KV[kidx(c4 + 0, row)] = (__bf16)preV[it].x;
            KV[kidx(c4 + 1, row)] = (__bf16)preV[it].y;
            KV[kidx(c4 + 2, row)] = (__bf16)preV[it].z;
            KV[kidx(c4 + 3, row)] = (__bf16)preV[it].w;
        }
    };

    auto do_tile = [&](int t) {
        const int r0  = t << 5;              // first query row of tile
        const int nct = (t + 2) >> 1;        // # of 64-col K/V tiles

        loadT(Kb, 0, preK);                  // prefetch round 0 early
        loadT(Vb, 0, preV);

        // ---- stage Q (32x64 f32) into KV, pull q-fragments ----
        BAR();                               // prev tile done with KV/Pl
        #pragma unroll
        for (int it = 0; it < 2; ++it) {
            int g = tid + (it << 8);
            int row = g >> 4, c4 = (g & 15) << 2;
            float4 v = *(const float4*)(Qb + (size_t)(r0 + row) * rowstride + c4);
            bf16x4_t w;
            w[0] = (__bf16)v.x; w[1] = (__bf16)v.y;
            w[2] = (__bf16)v.z; w[3] = (__bf16)v.w;
            *(bf16x4_t*)(KV + kidx(row, c4)) = w;
        }
        BAR();
        bf16x8_t qf0, qf1;
        {
            int row = (rg << 4) + l16;
            qf0 = *(bf16x8_t*)(KV + kidx(row, lq << 3));
            qf1 = *(bf16x8_t*)(KV + kidx(row, 32 + (lq << 3)));
        }

        const int rloc0 = (rg << 4) + (lq << 2);
        const int ig0   = r0 + rloc0;

        float psum[4] = {0.f, 0.f, 0.f, 0.f};
        f32x4_t accO0 = {0.f, 0.f, 0.f, 0.f};
        f32x4_t accO1 = {0.f, 0.f, 0.f, 0.f};

        // ================= pass A: e -> Pl, row sums, streamed stores =========
        for (int ct = 0; ct < nct; ++ct) {
            BAR();                           // qf / prev reads done
            writeK();
            if (ct + 1 < nct) loadT(Kb, ct + 1, preK);
            BAR();                           // K(ct) visible
            #pragma unroll
            for (int nn = 0; nn < 2; ++nn) {
                int ns = nsb + nn;
                int krow = (ns << 4) + l16;
                bf16x8_t k0 = *(bf16x8_t*)(KV + kidx(krow, lq << 3));
                bf16x8_t k1 = *(bf16x8_t*)(KV + kidx(krow, 32 + (lq << 3)));
                f32x4_t acc = {0.f, 0.f, 0.f, 0.f};
                acc = __builtin_amdgcn_mfma_f32_16x16x32_bf16(qf0, k0, acc, 0, 0, 0);
                acc = __builtin_amdgcn_mfma_f32_16x16x32_bf16(qf1, k1, acc, 0, 0, 0);
                int jg = (ct << 6) + (ns << 4) + l16;
                #pragma unroll
                for (int r = 0; r < 4; ++r) {
                    // no max-subtraction: scaled logits ~N(0,1), exp safe
                    float e = (jg <= ig0 + r) ? __expf(acc[r] * scale) : 0.f;
                    psum[r] += e;
                    Pl[pidx(rloc0 + r, jg)] = (__bf16)e;
                }
            }
            zslab();                         // zero-tail ser slab (8 KB)
            emit2();                         // 2 prior rows (16 KB)
        }

        // ---- row sums: reduce over l16 lanes, combine wave pairs ----
        #pragma unroll
        for (int r = 0; r < 4; ++r) {
            float s = psum[r];
            s += __shfl_xor(s, 1);
            s += __shfl_xor(s, 2);
            s += __shfl_xor(s, 4);
            s += __shfl_xor(s, 8);
            psum[r] = s;
        }
        if (l16 == 0) {
            #pragma unroll
            for (int r = 0; r < 4; ++r) rsum[wave][(lq << 2) + r] = psum[r];
        }
        BAR();
        if (tid < 32) {
            int rgx = tid >> 4;
            float tot = rsum[rgx << 1][tid & 15] + rsum[(rgx << 1) | 1][tid & 15];
            rinvs[tid] = 1.f / tot;
        }
        BAR();                               // rinvs visible

        // ================= pass B: PV + streamed normalized ser ==============
        loadT(Vb, 0, preV);
        for (int ct = 0; ct < nct; ++ct) {
            BAR();                           // prev KV reads done
            writeVt();
            if (ct + 1 < nct) loadT(Vb, ct + 1, preV);
            BAR();                           // V(ct) visible
            #pragma unroll
            for (int ks = 0; ks < 2; ++ks) {
                bf16x8_t pa = *(bf16x8_t*)(Pl + pidx((rg << 4) + l16,
                                             (ct << 6) + (ks << 5) + (lq << 3)));
                bf16x8_t vb0 = *(bf16x8_t*)(KV + kidx((nsb << 4) + l16,
                                             (ks << 5) + (lq << 3)));
                accO0 = __builtin_amdgcn_mfma_f32_16x16x32_bf16(pa, vb0, accO0, 0, 0, 0);
                bf16x8_t vb1 = *(bf16x8_t*)(KV + kidx(((nsb + 1) << 4) + l16,
                                             (ks << 5) + (lq << 3)));
                accO1 = __builtin_amdgcn_mfma_f32_16x16x32_bf16(pa, vb1, accO1, 0, 0, 0);
            }
            // ---- this round's normalized ser slab (8 KB) from Pl ----
            {
                bf16x8_t p8 = *(bf16x8_t*)(Pl + pidx(srow, (ct << 6) + scol));
                const float rv = rinvs[srow];
                float* dst = ser + ((size_t)(r0 + srow) << 10) + (ct << 6) + scol;
                f32x4_t o0, o1;
                o0.x = (float)p8[0] * rv; o0.y = (float)p8[1] * rv;
                o0.z = (float)p8[2] * rv; o0.w = (float)p8[3] * rv;
                o1.x = (float)p8[4] * rv; o1.y = (float)p8[5] * rv;
                o1.z = (float)p8[6] * rv; o1.w = (float)p8[7] * rv;
                __builtin_nontemporal_store(o0, (f32x4_t*)dst);
                __builtin_nontemporal_store(o1, (f32x4_t*)(dst + 4));
            }
            emit2();                         // 2 prior rows (16 KB)
        }

        // ---- V output [B,L,H,D], normalized ----
        #pragma unroll
        for (int r = 0; r < 4; ++r) {
            int rloc = rloc0 + r;
            float rv = rinvs[rloc];
            float* dst = outV + ((size_t)b * NL + r0 + rloc) * rowstride + h * NE;
            dst[(nsb << 4) + l16]       = accO0[r] * rv;
            dst[((nsb + 1) << 4) + l16] = accO1[r] * rv;
        }
    };

    do_tile(tA);
    do_tile(tB);

    // flush (normally empty: 17 pass-A rounds >= 15 slabs; 34 rounds >= 32)
    while (zs < 15) zslab();
    while (prow < 64) emit2();
}

extern "C" void kernel_launch(void* const* d_in, const int* in_sizes, int n_in,
                              void* d_out, int out_size, void* d_ws, size_t ws_size,
                              hipStream_t stream) {
    const float* Q  = (const float*)d_in[0];
    const float* K  = (const float*)d_in[1];
    const float* V  = (const float*)d_in[2];
    const float* Sg = (const float*)d_in[3];

    float* out      = (float*)d_out;
    float* outV     = out;                      // [4,1024,8,64]   = 2,097,152
    float* outSer   = out + 2097152;            // [4,8,1024,1024] = 33,554,432
    float* outPrior = out + 35651584;           // [4,8,1024,1024]
    float* outSig   = out + 69206016;           // [4,8,1024,1024]

    hipLaunchKernelGGL(fused_kernel, dim3(512), dim3(256), 0, stream,
                       Q, K, V, Sg, outV, outSer, outPrior, outSig);
}

// Round 10
// 85.392 us; speedup vs baseline: 1.5652x; 1.5652x over previous
//
#include <hip/hip_runtime.h>
#include <hip/hip_bf16.h>

// B=4, L=1024, H=8, E=D=64
#define NB 4
#define NL 1024
#define NH 8
#define NE 64
#define NPRIOR (NB * NH * NL)   // 32768 prior rows (= 1024 blocks x 32 exactly)

typedef __bf16 bf16x8_t __attribute__((ext_vector_type(8)));
typedef __bf16 bf16x4_t __attribute__((ext_vector_type(4)));
typedef float f32x4_t __attribute__((ext_vector_type(4)));

// XOR swizzle (T2): elem ^= (row&7)<<3 spreads 128B-stride rows over banks.
__device__ __forceinline__ int kidx(int row, int col) {   // 64-wide tiles
    return (row << 6) + (col ^ ((row & 7) << 3));
}
__device__ __forceinline__ int pidx(int row, int col) {   // 1024-wide P tile
    return (row << 10) + (col ^ ((row & 7) << 3));
}

// T4-style barrier: drain LDS ops (visibility) but leave global loads/stores
// in flight (no vmcnt(0) drain like __syncthreads).
#define BAR() do { asm volatile("s_waitcnt lgkmcnt(0)" ::: "memory"); \
                   __builtin_amdgcn_s_barrier();                      \
                   asm volatile("" ::: "memory"); } while (0)

// 1024 blocks (3/CU, ~41 KB LDS), 4 waves. Block (p=bid&31, jp=bid>>5) owns
// the balanced 16-row tile pair (63-jp, jp): nctA+nctB == 17 fused rounds for
// EVERY block. Round structure identical to the measured-87us r5 kernel:
// BAR / writeK+prefetch / BAR / QK^T MFMA -> e once into Pl (32 KB) + row sums
// / BAR / writeVt+prefetch / BAR / PV MFMA / 2 prior rows (NT stores).
// After rounds: rinv reduce, V out, coalesced normalized ser sweep (+0 tail).
// vs r5: strip 32->16 rows halves Pl -> 3 blocks/CU (was 2) for smoother
// store issue and better latency overlap; sweep bursts halve.
__global__ __launch_bounds__(256, 3) void fused_kernel(
    const float* __restrict__ Qg, const float* __restrict__ Kg,
    const float* __restrict__ Vg, const float* __restrict__ Sgm,
    float* __restrict__ outV, float* __restrict__ outSer,
    float* __restrict__ outP, float* __restrict__ outSig)
{
    __shared__ __bf16 Pl[16 * 1024];   // 32 KB e-values for the 16-row strip
    __shared__ __bf16 KV[64 * 64];     // 8 KB shared Q/K/V staging
    __shared__ float rsum[4][16];
    __shared__ float rinvs[16];
    __shared__ float sgl[32], cstl[32], nil[32];   // prior per-row constants

    const int bid = blockIdx.x;        // 0..1023
    const int p  = bid & 31;           // b*8 + h (same-p blocks share an XCD)
    const int jp = bid >> 5;           // 0..31 pair index
    const int h = p & 7, b = p >> 3;
    const int tid = threadIdx.x;
    const int lane = tid & 63, wave = tid >> 6;
    const int l16 = lane & 15, lq = lane >> 4;
    const int nc  = wave;              // this wave's 16-col key/d group (0..3)
    const int rowstride = NH * NE;     // 512 floats per (b,l) row

    const float* Qb = Qg + ((size_t)b * NL) * rowstride + h * NE;
    const float* Kb = Kg + ((size_t)b * NL) * rowstride + h * NE;
    const float* Vb = Vg + ((size_t)b * NL) * rowstride + h * NE;
    float* ser = outSer + ((size_t)p << 20);
    const float scale = 0.125f;        // 1/sqrt(64)

    // ---- prior constants for this block's 32 rows ----
    if (tid < 32) {
        const int g  = (bid << 5) + tid;
        const int i  = g & (NL - 1);
        const int ph = g >> 10;
        const float s   = Sgm[((size_t)(ph >> 3) * NL + i) * NH + (ph & 7)];
        const float sig = 1.f / (1.f + __expf(-5.f * s)) + 1e-5f;
        // 3^sig - 1 via expm1 (avoids cancellation at sig ~ 1e-5)
        const float sg  = expm1f(sig * 1.0986122886681098f);
        sgl[tid]  = sg;
        cstl[tid] = 0.3989422804014327f / sg;
        nil[tid]  = -0.5f / (sg * sg);
    }

    int prow = 0;
    auto emit2 = [&]() {               // 2 prior+sig rows (16 KB) per round
        if (prow < 32) {
            #pragma unroll
            for (int c = 0; c < 2; ++c) {
                const int lr = prow + c;
                const int g  = (bid << 5) + lr;
                const int i  = g & (NL - 1);
                const int ph = g >> 10;
                const float sg  = sgl[lr];
                const float cst = cstl[lr];
                const float ni  = nil[lr];
                const size_t ob = ((size_t)ph << 20) + ((size_t)i << 10);
                const int j0 = tid << 2;
                const float fd = (float)(i - j0);
                f32x4_t pr;
                pr.x = cst * __expf(fd * fd * ni);
                const float f1 = fd - 1.f; pr.y = cst * __expf(f1 * f1 * ni);
                const float f2 = fd - 2.f; pr.z = cst * __expf(f2 * f2 * ni);
                const float f3 = fd - 3.f; pr.w = cst * __expf(f3 * f3 * ni);
                __builtin_nontemporal_store(pr, (f32x4_t*)(outP + ob + j0));
                f32x4_t sv = {sg, sg, sg, sg};
                __builtin_nontemporal_store(sv, (f32x4_t*)(outSig + ob + j0));
            }
            prow += 2;
        }
    };

    float4 preK[4], preV[4];
    auto loadT = [&](const float* base, int ct, float4 (&dst)[4]) {
        const float* src = base + ((size_t)(ct << 6)) * rowstride;
        #pragma unroll
        for (int it = 0; it < 4; ++it) {
            int g = tid + (it << 8);
            int row = g >> 4, c4 = (g & 15) << 2;
            dst[it] = *(const float4*)(src + (size_t)row * rowstride + c4);
        }
    };
    auto writeK = [&]() {
        #pragma unroll
        for (int it = 0; it < 4; ++it) {
            int g = tid + (it << 8);
            int row = g >> 4, c4 = (g & 15) << 2;
            bf16x4_t w;
            w[0] = (__bf16)preK[it].x; w[1] = (__bf16)preK[it].y;
            w[2] = (__bf16)preK[it].z; w[3] = (__bf16)preK[it].w;
            *(bf16x4_t*)(KV + kidx(row, c4)) = w;
        }
    };
    auto writeVt = [&]() {   // transposed: KV[d][j]
        #pragma unroll
        for (int it = 0; it < 4; ++it) {
            int g = tid + (it << 8);
            int row = g >> 4, c4 = (g & 15) << 2;   // row=j, c4=d
            KV[kidx(c4 + 0, row)] = (__bf16)preV[it].x;
            KV[kidx(c4 + 1, row)] = (__bf16)preV[it].y;
            KV[kidx(c4 + 2, row)] = (__bf16)preV[it].z;
            KV[kidx(c4 + 3, row)] = (__bf16)preV[it].w;
        }
    };

    auto do_tile = [&](int t) {
        const int r0  = t << 4;              // first query row of tile (16-row)
        const int nct = (t >> 2) + 1;        // # of 64-col K/V tiles

        loadT(Kb, 0, preK);                  // prefetch round 0 early
        loadT(Vb, 0, preV);

        // ---- stage Q (16x64 f32) into KV, pull q-fragments ----
        BAR();                               // prev tile done with KV/Pl
        {
            int row = tid >> 4, c4 = (tid & 15) << 2;   // 256 granules
            float4 v = *(const float4*)(Qb + (size_t)(r0 + row) * rowstride + c4);
            bf16x4_t w;
            w[0] = (__bf16)v.x; w[1] = (__bf16)v.y;
            w[2] = (__bf16)v.z; w[3] = (__bf16)v.w;
            *(bf16x4_t*)(KV + kidx(row, c4)) = w;
        }
        BAR();
        bf16x8_t qf0, qf1;
        {
            qf0 = *(bf16x8_t*)(KV + kidx(l16, lq << 3));
            qf1 = *(bf16x8_t*)(KV + kidx(l16, 32 + (lq << 3)));
        }

        const int rloc0 = lq << 2;           // this thread's 4 query rows
        const int ig0   = r0 + rloc0;

        float psum[4] = {0.f, 0.f, 0.f, 0.f};
        f32x4_t accO = {0.f, 0.f, 0.f, 0.f};

        for (int ct = 0; ct < nct; ++ct) {
            BAR();                           // qf / prev-V reads done
            writeK();
            if (ct + 1 < nct) loadT(Kb, ct + 1, preK);
            BAR();                           // K(ct) visible
            // ---- QK^T: this wave's 16-key group ----
            {
                int krow = (nc << 4) + l16;
                bf16x8_t k0 = *(bf16x8_t*)(KV + kidx(krow, lq << 3));
                bf16x8_t k1 = *(bf16x8_t*)(KV + kidx(krow, 32 + (lq << 3)));
                f32x4_t acc = {0.f, 0.f, 0.f, 0.f};
                acc = __builtin_amdgcn_mfma_f32_16x16x32_bf16(qf0, k0, acc, 0, 0, 0);
                acc = __builtin_amdgcn_mfma_f32_16x16x32_bf16(qf1, k1, acc, 0, 0, 0);
                int jg = (ct << 6) + (nc << 4) + l16;
                #pragma unroll
                for (int r = 0; r < 4; ++r) {
                    // no max-subtraction: scaled logits ~N(0,1), exp safe
                    float e = (jg <= ig0 + r) ? __expf(acc[r] * scale) : 0.f;
                    psum[r] += e;
                    Pl[pidx(rloc0 + r, jg)] = (__bf16)e;
                }
            }
            BAR();                           // Pl(ct) written; K reads done
            writeVt();
            if (ct + 1 < nct) loadT(Vb, ct + 1, preV);
            BAR();                           // V(ct) visible
            // ---- PV: O += P * V (this wave's 16-d group) ----
            #pragma unroll
            for (int ks = 0; ks < 2; ++ks) {
                bf16x8_t pa = *(bf16x8_t*)(Pl + pidx(l16,
                                             (ct << 6) + (ks << 5) + (lq << 3)));
                bf16x8_t vb = *(bf16x8_t*)(KV + kidx((nc << 4) + l16,
                                             (ks << 5) + (lq << 3)));
                accO = __builtin_amdgcn_mfma_f32_16x16x32_bf16(pa, vb, accO, 0, 0, 0);
            }
            emit2();                         // prior writes overlap next round
        }

        // ---- row sums: reduce over l16 lanes, combine 4 waves ----
        #pragma unroll
        for (int r = 0; r < 4; ++r) {
            float s = psum[r];
            s += __shfl_xor(s, 1);
            s += __shfl_xor(s, 2);
            s += __shfl_xor(s, 4);
            s += __shfl_xor(s, 8);
            psum[r] = s;
        }
        if (l16 == 0) {
            #pragma unroll
            for (int r = 0; r < 4; ++r) rsum[wave][(lq << 2) + r] = psum[r];
        }
        BAR();
        if (tid < 16) {
            rinvs[tid] = 1.f / (rsum[0][tid] + rsum[1][tid] +
                                rsum[2][tid] + rsum[3][tid]);
        }
        BAR();                               // rinvs visible

        // ---- V output [B,L,H,D], normalized ----
        #pragma unroll
        for (int r = 0; r < 4; ++r) {
            int rloc = rloc0 + r;
            float rv = rinvs[rloc];
            float* dst = outV + ((size_t)b * NL + r0 + rloc) * rowstride + h * NE;
            dst[(nc << 4) + l16] = accO[r] * rv;
        }

        // ---- series sweep: coalesced float4 writes + zero tail ----
        const int lim = nct << 6;
        #pragma unroll
        for (int rr = wave; rr < 16; rr += 4) {
            float rv = rinvs[rr];
            float* dst = ser + ((size_t)(r0 + rr) << 10);
            #pragma unroll
            for (int k = 0; k < 4; ++k) {
                int col = (lane << 2) + (k << 8);
                f32x4_t o;
                if (col < lim) {
                    bf16x4_t p4 = *(bf16x4_t*)(Pl + pidx(rr, col));
                    o.x = (float)p4[0] * rv;
                    o.y = (float)p4[1] * rv;
                    o.z = (float)p4[2] * rv;
                    o.w = (float)p4[3] * rv;
                } else {
                    o.x = 0.f; o.y = 0.f; o.z = 0.f; o.w = 0.f;
                }
                __builtin_nontemporal_store(o, (f32x4_t*)(dst + col));
            }
        }
    };

    do_tile(63 - jp);
    do_tile(jp);

    // flush (normally empty: 17 rounds x 2 = 34 >= 32)
    while (prow < 32) emit2();
}

extern "C" void kernel_launch(void* const* d_in, const int* in_sizes, int n_in,
                              void* d_out, int out_size, void* d_ws, size_t ws_size,
                              hipStream_t stream) {
    const float* Q  = (const float*)d_in[0];
    const float* K  = (const float*)d_in[1];
    const float* V  = (const float*)d_in[2];
    const float* Sg = (const float*)d_in[3];

    float* out      = (float*)d_out;
    float* outV     = out;                      // [4,1024,8,64]   = 2,097,152
    float* outSer   = out + 2097152;            // [4,8,1024,1024] = 33,554,432
    float* outPrior = out + 35651584;           // [4,8,1024,1024]
    float* outSig   = out + 69206016;           // [4,8,1024,1024]

    hipLaunchKernelGGL(fused_kernel, dim3(1024), dim3(256), 0, stream,
                       Q, K, V, Sg, outV, outSer, outPrior, outSig);
}